// Round 9
// baseline (554.007 us; speedup 1.0000x reference)
//
#include <hip/hip_runtime.h>
#include <float.h>
#include <math.h>

#define NB 2
#define MQ 16384
#define NQ (NB*MQ)          // 32768 queries
#define PP 5023
#define KNN 4
#define HPX 256
#define HWSZ (HPX*HPX)      // 65536
#define GD 12               // grid dim
#define GC (GD*GD*GD)       // 1728 cells

// output layout (floats): densities[NQ], rgb[NQ*32], dist[NQ*4]
#define OUT_RGB_OFF  ((size_t)NQ)
#define OUT_DIST_OFF ((size_t)NQ + (size_t)NQ*32)

// workspace layout (bytes)
#define WS_SUMS_OFF   ((size_t)0x80000)
#define WS_CNT_OFF    ((size_t)0x81000)      // 2*1728*4 = 13824
#define WS_START_OFF  ((size_t)0x85000)
#define WS_CURSOR_OFF ((size_t)0x89000)
#define WS_PG_OFF     ((size_t)0x90000)      // 2*5023*16 = 160736
#define WS_PID_OFF    ((size_t)0xB8000)      // 2*5023*4
#define WS_WP_OFF     ((size_t)0xC8000)      // 29504 u32 = 118016 B
#define WS_TEX_OFF    ((size_t)1<<20)        // 48 MB transposed tex

// packed-weight sub-offsets (u32 units)
#define WP_PW1 0
#define WP_PW2 1920
#define WP_FW1 2944
#define WP_FW2 7040
#define WP_FW3 15232
#define WP_DW  23424
#define WP_RW1 23488
#define WP_RW2 28480

typedef __attribute__((ext_vector_type(2))) _Float16 half2v;

static __device__ __forceinline__ unsigned int pk2(float a, float b) {
    half2v h; h[0] = (_Float16)a; h[1] = (_Float16)b;   // RNE converts
    return __builtin_bit_cast(unsigned int, h);
}
static __device__ __forceinline__ float2 upk(unsigned int u) {
    half2v h = __builtin_bit_cast(half2v, u);
    return make_float2((float)h[0], (float)h[1]);
}
static __device__ __forceinline__ float dot2(unsigned int a, unsigned int b, float c) {
    return __builtin_amdgcn_fdot2(__builtin_bit_cast(half2v, a),
                                  __builtin_bit_cast(half2v, b), c, false);
}

static __device__ __forceinline__ int cell_of(float x) {
    int g = (int)(x * (float)GD);
    return (g < 0) ? 0 : ((g > GD-1) ? GD-1 : g);
}

// ------------------------------------------------------------------
// weight pack: fp32 [DIN][DOUT] -> f16x2 [(DIN+1)/2][DOUT] (pairs across DIN)
struct PackArgs {
    const float* src[8];
    int off[8]; int din[8]; int dout[8];
};
__global__ __launch_bounds__(256) void k_pack(PackArgs a, unsigned int* wp) {
    const int mid = blockIdx.y;
    const int idx = blockIdx.x * 256 + threadIdx.x;
    const int DIN = a.din[mid], DOUT = a.dout[mid];
    const int din2 = (DIN + 1) >> 1;
    if (idx >= din2 * DOUT) return;
    const int i2 = idx / DOUT, j = idx - i2 * DOUT;
    const float* s = a.src[mid];
    const float lo = s[(2*i2) * DOUT + j];
    const float hi = (2*i2 + 1 < DIN) ? s[(2*i2 + 1) * DOUT + j] : 0.f;
    wp[a.off[mid] + idx] = pk2(lo, hi);
}

// ------------------------------------------------------------------
// texture transpose: [n3][32][HW] -> [n3][HW][32]
__global__ __launch_bounds__(256) void k_transpose(const float* __restrict__ src,
                                                   float* __restrict__ dst) {
    const int tid = threadIdx.x;
    const int b = blockIdx.x;            // 6*256 blocks
    const int n3 = b >> 8;
    const int hw = ((b & 255) << 8) + tid;
    const float* s = src + (size_t)n3 * 32 * HWSZ + hw;
    float v[32];
#pragma unroll
    for (int c = 0; c < 32; ++c) v[c] = s[(size_t)c * HWSZ];
    float4* d = (float4*)(dst + ((size_t)n3 * HWSZ + hw) * 32);
#pragma unroll
    for (int c = 0; c < 8; ++c) d[c] = make_float4(v[4*c], v[4*c+1], v[4*c+2], v[4*c+3]);
}

// ------------------------------------------------------------------
// grid build: count -> scan -> scatter
__global__ __launch_bounds__(256) void k_gcount(const float* __restrict__ pts,
                                                unsigned int* __restrict__ cnt) {
    const int i = blockIdx.x * 256 + threadIdx.x;
    if (i >= NB * PP) return;
    const int n = (i >= PP) ? 1 : 0;
    const float px = pts[3*i], py = pts[3*i+1], pz = pts[3*i+2];
    const int c = (cell_of(pz)*GD + cell_of(py))*GD + cell_of(px);
    atomicAdd(&cnt[n*GC + c], 1u);
}

__global__ __launch_bounds__(1024) void k_gscan(const unsigned int* __restrict__ cnt,
                                                unsigned int* __restrict__ start,
                                                unsigned int* __restrict__ cursor) {
    __shared__ unsigned int sc[1024];
    const int t = threadIdx.x;
#pragma unroll 1
    for (int n = 0; n < 2; ++n) {
        const unsigned int* c = cnt + n*GC;
        unsigned int a = (2*t   < GC) ? c[2*t]   : 0u;
        unsigned int b = (2*t+1 < GC) ? c[2*t+1] : 0u;
        unsigned int s = a + b;
        sc[t] = s;
        __syncthreads();
        for (int off = 1; off < 1024; off <<= 1) {
            unsigned int v = (t >= off) ? sc[t - off] : 0u;
            __syncthreads();
            sc[t] += v;
            __syncthreads();
        }
        unsigned int excl = sc[t] - s;
        unsigned int base = n * PP;
        if (2*t < GC)   { start[n*GC + 2*t]   = base + excl;
                          cursor[n*GC + 2*t]  = base + excl; }
        if (2*t+1 < GC) { start[n*GC + 2*t+1] = base + excl + a;
                          cursor[n*GC + 2*t+1]= base + excl + a; }
        __syncthreads();
    }
}

__global__ __launch_bounds__(256) void k_gscatter(const float* __restrict__ pts,
                                                  unsigned int* __restrict__ cursor,
                                                  float4* __restrict__ pg,
                                                  int* __restrict__ pid) {
    const int i = blockIdx.x * 256 + threadIdx.x;
    if (i >= NB * PP) return;
    const int n = (i >= PP) ? 1 : 0;
    const int local = i - n * PP;
    const float px = pts[3*i], py = pts[3*i+1], pz = pts[3*i+2];
    const int c = (cell_of(pz)*GD + cell_of(py))*GD + cell_of(px);
    const unsigned int pos = atomicAdd(&cursor[n*GC + c], 1u);
    pg[pos] = make_float4(px, py, pz, fmaf(px, px, fmaf(py, py, pz*pz)));
    pid[pos] = local;
}

// ------------------------------------------------------------------
// grid KNN: one thread per query; expanding Chebyshev rings with a
// conservative stop bound; exact reference-formula d2 + index tie-break.
__global__ __launch_bounds__(256) void k_knn_grid(
    const float* __restrict__ coords,
    const unsigned int* __restrict__ cellStart,
    const unsigned int* __restrict__ cellCnt,
    const float4* __restrict__ pg, const int* __restrict__ pid,
    float* __restrict__ odist, int* __restrict__ oidx)
{
    const int q = blockIdx.x * 256 + threadIdx.x;   // 32768
    const int n = q >> 14;
    const float cx = coords[q*3+0], cy = coords[q*3+1], cz = coords[q*3+2];
    const float cc = fmaf(cx, cx, fmaf(cy, cy, cz*cz));
    const int cb = n * GC;
    const int gx = cell_of(cx), gy = cell_of(cy), gz = cell_of(cz);
    const float w = 1.0f / (float)GD;

    float bd0 = FLT_MAX, bd1 = FLT_MAX, bd2 = FLT_MAX, bd3 = FLT_MAX;
    int   bi0 = 0x7fffffff, bi1 = 0x7fffffff, bi2 = 0x7fffffff, bi3 = 0x7fffffff;

#pragma unroll 1
    for (int r = 0; r < GD; ++r) {
        const int x0 = max(gx-r, 0), x1 = min(gx+r, GD-1);
        const int y0 = max(gy-r, 0), y1 = min(gy+r, GD-1);
        const int z0 = max(gz-r, 0), z1 = min(gz+r, GD-1);
#pragma unroll 1
        for (int zz = z0; zz <= z1; ++zz)
#pragma unroll 1
        for (int yy = y0; yy <= y1; ++yy)
#pragma unroll 1
        for (int xx = x0; xx <= x1; ++xx) {
            const int chb = max(abs(xx-gx), max(abs(yy-gy), abs(zz-gz)));
            if (chb != r) continue;
            const int cid = cb + (zz*GD + yy)*GD + xx;
            const unsigned int s = cellStart[cid];
            const unsigned int e = s + cellCnt[cid];
#pragma unroll 1
            for (unsigned int j = s; j < e; ++j) {
                const float4 P = pg[j];
                const int i = pid[j];
                const float dt = fmaf(cx, P.x, fmaf(cy, P.y, cz * P.z));
                const float d = fmaf(-2.0f, dt, cc + P.w);
                bool L3 = (d < bd3) || (d == bd3 && i < bi3);
                bool L2 = (d < bd2) || (d == bd2 && i < bi2);
                bool L1 = (d < bd1) || (d == bd1 && i < bi1);
                bool L0 = (d < bd0) || (d == bd0 && i < bi0);
                bd3 = L3 ? (L2 ? bd2 : d) : bd3;  bi3 = L3 ? (L2 ? bi2 : i) : bi3;
                bd2 = L2 ? (L1 ? bd1 : d) : bd2;  bi2 = L2 ? (L1 ? bi1 : i) : bi2;
                bd1 = L1 ? (L0 ? bd0 : d) : bd1;  bi1 = L1 ? (L0 ? bi0 : i) : bi1;
                bd0 = L0 ? d : bd0;               bi0 = L0 ? i : bi0;
            }
        }
        if (bd3 < FLT_MAX) {
            const float rr = (float)r * w;
            if (bd3 <= rr * rr * 0.9999f) break;
        }
    }
    *(float4*)(odist + (size_t)q*4) = make_float4(bd0, bd1, bd2, bd3);
    *(int4*)(oidx + (size_t)q*4)    = make_int4(bi0, bi1, bi2, bi3);
}

// ------------------------------------------------------------------
// per-(n,k) sum over m of 1/dist (deterministic)
__global__ __launch_bounds__(1024) void k_sums(const float* __restrict__ dist,
                                               float* __restrict__ sums) {
    const int b = blockIdx.x;            // n*4+k, 8 blocks
    const int n = b >> 2, k = b & 3;
    float s = 0.f;
    for (int m = threadIdx.x; m < MQ; m += 1024)
        s += 1.0f / dist[((size_t)n * MQ + m) * 4 + k];
    __shared__ float red[1024];
    red[threadIdx.x] = s;
    __syncthreads();
    for (int off = 512; off > 0; off >>= 1) {
        if (threadIdx.x < off) red[threadIdx.x] += red[threadIdx.x + off];
        __syncthreads();
    }
    if (threadIdx.x == 0) sums[b] = red[0];
}

// ------------------------------------------------------------------
// packed gemv: activations f16x2 from LDS (col = lane); weights f16x2 via
// PER-LANE vector loads (wv kept divergent -> global_load, L1 broadcast,
// vmcnt-pipelined; NOT s_load -> no lgkmcnt(0) serialization).
template<int DIN2, int DOUT, int TILE>
__device__ __forceinline__ void gemv_p(const unsigned int* __restrict__ Xp, int lane,
                                       const unsigned int* __restrict__ Wp,
                                       const float* __restrict__ bias,
                                       int j0, float (&acc)[TILE]) {
#pragma unroll
    for (int u = 0; u < TILE; ++u) acc[u] = bias[j0 + u];
#pragma unroll
    for (int i2 = 0; i2 < DIN2; ++i2) {
        const unsigned int xv = Xp[i2 * 64 + lane];
        const unsigned int* wr = Wp + i2 * DOUT + j0;
#pragma unroll
        for (int u = 0; u < TILE; ++u) acc[u] = dot2(xv, wr[u], acc[u]);
    }
}

// harmonic value h of [sin x12, cos x12, r x3]
static __device__ __forceinline__ float harm_val(int h, float rx, float ry, float rz) {
    if (h >= 27) return 0.f;
    float v;
    if (h < 24) {
        int base = (h < 12) ? h : (h - 12);
        float rv = (base >> 2) == 0 ? rx : ((base >> 2) == 1 ? ry : rz);
        float e = rv * (float)(1 << (base & 3));
        v = (h < 12) ? sinf(e) : cosf(e);
    } else {
        v = (h == 24) ? rx : ((h == 25) ? ry : rz);
    }
    return v;
}

// ------------------------------------------------------------------
// main fused kernel v9: R7 phase structure, but wv DIVERGENT (vector weight
// loads) and launch_bounds(1024,1) -> VGPR cap 128, no spill possible.
__global__ __launch_bounds__(1024, 1) void k_main(
    const float* __restrict__ coords, const float* __restrict__ dirs,
    const float* __restrict__ pts, const float* __restrict__ tex_raw,
    const float* __restrict__ tex_t, const float* __restrict__ emb,
    const unsigned int* __restrict__ wp,
    const float* __restrict__ pb1, const float* __restrict__ pb2,
    const float* __restrict__ fb1, const float* __restrict__ fb2,
    const float* __restrict__ fb3, const float* __restrict__ db,
    const float* __restrict__ rb1, const float* __restrict__ rb2,
    const int* __restrict__ idxbuf, const float* __restrict__ distbuf,
    const float* __restrict__ sums, float* __restrict__ out, int use_tex_t)
{
    __shared__ unsigned int S[248 * 64];   // 62 KB
    const int tid  = threadIdx.x;
    const int lane = tid & 63;
    const int wv   = tid >> 6;             // divergent on purpose (vector loads)
    const int q0   = blockIdx.x * 64;
    const int n    = q0 >> 14;
    const int q    = q0 + lane;

    // ---------- phase 0: triplane sampling -> fp32 regs (2 ch/wave) ----------
    float tex_acc[2] = {0.f, 0.f};
    {
        const int g = wv;
        const float cx = coords[q*3+0], cy = coords[q*3+1], cz = coords[q*3+2];
#pragma unroll
        for (int pl = 0; pl < 3; ++pl) {
            float gx = (pl == 2) ? cz : cx;
            float gy = (pl == 0) ? cy : ((pl == 1) ? cz : cx);
            float x = (gx + 1.f) * 128.f - 0.5f;
            float y = (gy + 1.f) * 128.f - 0.5f;
            float x0f = floorf(x), y0f = floorf(y);
            float wx1 = x - x0f, wy1 = y - y0f;
            float wx0 = 1.f - wx1, wy0 = 1.f - wy1;
            int x0 = (int)x0f, y0 = (int)y0f;
            int n3 = n * 3 + pl;
            int  xs[4] = { x0, x0+1, x0,   x0+1 };
            int  ys[4] = { y0, y0,   y0+1, y0+1 };
            float wt[4] = { wx0*wy0, wx1*wy0, wx0*wy1, wx1*wy1 };
#pragma unroll
            for (int c = 0; c < 4; ++c) {
                int xi = xs[c], yi = ys[c];
                if (xi >= 0 && xi < HPX && yi >= 0 && yi < HPX) {
                    float wgt = wt[c];
                    if (use_tex_t) {
                        const float2 a = *(const float2*)(tex_t +
                            (((size_t)n3 * HWSZ + (size_t)yi * HPX + xi) * 32 + g * 2));
                        tex_acc[0] = fmaf(wgt, a.x, tex_acc[0]);
                        tex_acc[1] = fmaf(wgt, a.y, tex_acc[1]);
                    } else {
                        size_t base = ((size_t)(n3 * 32 + g * 2)) * HWSZ + (size_t)yi * HPX + xi;
                        tex_acc[0] = fmaf(wgt, tex_raw[base], tex_acc[0]);
                        tex_acc[1] = fmaf(wgt, tex_raw[base + HWSZ], tex_acc[1]);
                    }
                }
            }
        }
        tex_acc[0] *= (1.f / 3.f); tex_acc[1] *= (1.f / 3.f);
    }

    const int kk  = wv & 3;      // neighbor index this wave handles
    const int prt = wv >> 2;     // 0..3 part / j-slice

    // ---------- phase A: build x59 for ALL 4 neighbors (rows kk*30 + r) ----------
    {
        const int id = idxbuf[(size_t)q*4 + kk];
        const int rb = kk * 30;
        if (prt < 2) {
#pragma unroll
            for (int t = 0; t < 2; ++t) {
                const float4 e = *(const float4*)(emb + (size_t)id * 32 + prt*16 + t*4 + 0)
                    , e2 = *(const float4*)(emb + (size_t)id * 32 + prt*16 + t*4 + 8);
                S[(rb + prt*8 + t*2    )*64 + lane] = pk2(e.x,  e.y);
                S[(rb + prt*8 + t*2 + 1)*64 + lane] = pk2(e.z,  e.w);
                S[(rb + prt*8 + t*2 + 4)*64 + lane] = pk2(e2.x, e2.y);
                S[(rb + prt*8 + t*2 + 5)*64 + lane] = pk2(e2.z, e2.w);
            }
        } else {
            const float cx = coords[q*3+0], cy = coords[q*3+1], cz = coords[q*3+2];
            const float nx = pts[((size_t)n*PP + id)*3 + 0];
            const float ny = pts[((size_t)n*PP + id)*3 + 1];
            const float nz = pts[((size_t)n*PP + id)*3 + 2];
            float rx = cx - nx, ry = cy - ny, rz = cz - nz;
            float nrm = sqrtf(fmaf(rx, rx, fmaf(ry, ry, rz*rz)));
            float inv = 1.f / fmaxf(nrm, 1e-12f);
            rx *= inv; ry *= inv; rz *= inv;
            const int pr0 = (prt == 2) ? 0 : 8;
            const int prn = (prt == 2) ? 8 : 6;
#pragma unroll
            for (int t = 0; t < 8; ++t) {
                if (t < prn) {
                    int pr = pr0 + t;
                    S[(rb + 16 + pr)*64 + lane] =
                        pk2(harm_val(2*pr, rx, ry, rz), harm_val(2*pr + 1, rx, ry, rz));
                }
            }
        }
    }
    __syncthreads();

    // ---------- phase B: p1 59->64 relu for all k; wave (kk, j0=prt*16) ----------
    {
        float acc[16];
        gemv_p<30, 64, 16>(S + (kk*30)*64, lane, wp + WP_PW1, pb1, prt * 16, acc);
        const int rb = 120 + kk*32 + prt*8;
#pragma unroll
        for (int u = 0; u < 8; ++u)
            S[(rb + u)*64 + lane] = pk2(fmaxf(acc[2*u], 0.f), fmaxf(acc[2*u+1], 0.f));
    }
    __syncthreads();

    // ---------- phase C: p2 64->32 for all k, wk-scaled -> rows kk*16 + r ----------
    {
        float acc[8];
        gemv_p<32, 32, 8>(S + (120 + kk*32)*64, lane, wp + WP_PW2, pb2, prt * 8, acc);
        const float dist = distbuf[(size_t)q*4 + kk];
        const float wk = (1.0f / dist) / sums[n*4 + kk];
        const int rb = kk*16 + prt*4;
#pragma unroll
        for (int u = 0; u < 4; ++u)
            S[(rb + u)*64 + lane] = pk2(wk * acc[2*u], wk * acc[2*u+1]);
    }
    __syncthreads();

    // ---------- phase D: feat -> rows 128..159 (tex 128..143, pts 144..159) ----------
    {
        S[(128 + wv)*64 + lane] = pk2(tex_acc[0], tex_acc[1]);
        float a = 0.f, b = 0.f;
#pragma unroll
        for (int k = 0; k < 4; ++k) {
            float2 v = upk(S[(k*16 + wv)*64 + lane]);
            a += v.x; b += v.y;
        }
        S[(144 + wv)*64 + lane] = pk2(a, b);
    }
    __syncthreads();

    // ---------- phase E: fw1 64->128 relu, rows 128..159 -> rows 0..63 ----------
    {
        float acc[8];
        gemv_p<32, 128, 8>(S + 128*64, lane, wp + WP_FW1, fb1, wv * 8, acc);
#pragma unroll
        for (int u = 0; u < 4; ++u)
            S[(4*wv + u)*64 + lane] = pk2(fmaxf(acc[2*u], 0.f), fmaxf(acc[2*u+1], 0.f));
    }
    __syncthreads();
    // ---------- phase F: fw2 128->128 relu, rows 0..63 -> rows 64..127 ----------
    {
        float acc[8];
        gemv_p<64, 128, 8>(S, lane, wp + WP_FW2, fb2, wv * 8, acc);
#pragma unroll
        for (int u = 0; u < 4; ++u)
            S[(64 + 4*wv + u)*64 + lane] = pk2(fmaxf(acc[2*u], 0.f), fmaxf(acc[2*u+1], 0.f));
    }
    __syncthreads();
    // ---------- phase G: fw3 128->128, rows 64..127 -> rows 0..63 ----------
    {
        float acc[8];
        gemv_p<64, 128, 8>(S + 64*64, lane, wp + WP_FW3, fb3, wv * 8, acc);
#pragma unroll
        for (int u = 0; u < 4; ++u)
            S[(4*wv + u)*64 + lane] = pk2(acc[2*u], acc[2*u+1]);
    }
    __syncthreads();
    // ---------- phase H: ray harm -> rows 128..141; density (wave 15) ----------
    {
        if (wv < 14) {
            float dx = dirs[q*3+0], dy = dirs[q*3+1], dz = dirs[q*3+2];
            float dn = sqrtf(fmaf(dx, dx, fmaf(dy, dy, dz*dz)));
            float inv = 1.f / fmaxf(dn, 1e-12f);
            dx *= inv; dy *= inv; dz *= inv;
            S[(128 + wv)*64 + lane] = pk2(harm_val(2*wv, dx, dy, dz),
                                          harm_val(2*wv + 1, dx, dy, dz));
        } else if (wv == 15) {
            float z = db[0];
            const unsigned int* dwp = wp + WP_DW;
#pragma unroll 1
            for (int i2 = 0; i2 < 64; ++i2) z = dot2(S[i2*64 + lane], dwp[i2], z);
            const float cx = coords[q*3+0], cy = coords[q*3+1], cz = coords[q*3+2];
            float selv = (cx > -1.f && cx < 1.f && cy > -1.f && cy < 1.f &&
                          cz > -1.f && cz < 1.f) ? 1.f : 0.f;
            float t10 = 10.f * z;
            float sp = (t10 > 20.f) ? t10 : log1pf(expf(t10));
            float raw = sp * 0.1f * selv;
            out[q] = 1.f - expf(-raw);
        }
    }
    __syncthreads();
    // ---------- phase I: rw1 155->64 relu; feat rows 0..63 + harm 128..141 -> 64..95 ----------
    {
        const int j0 = wv * 4;
        float acc[4];
        gemv_p<64, 64, 4>(S, lane, wp + WP_RW1, rb1, j0, acc);
#pragma unroll
        for (int t = 0; t < 14; ++t) {
            const unsigned int xv = S[(128 + t)*64 + lane];
            const unsigned int* wr = wp + WP_RW1 + (64 + t) * 64 + j0;
#pragma unroll
            for (int u = 0; u < 4; ++u) acc[u] = dot2(xv, wr[u], acc[u]);
        }
        S[(64 + 2*wv    )*64 + lane] = pk2(fmaxf(acc[0], 0.f), fmaxf(acc[1], 0.f));
        S[(64 + 2*wv + 1)*64 + lane] = pk2(fmaxf(acc[2], 0.f), fmaxf(acc[3], 0.f));
    }
    __syncthreads();
    // ---------- phase J: rw2 64->32, sigmoid on first 3; rows 64..95 -> out ----------
    {
        float acc[2];
        gemv_p<32, 32, 2>(S + 64*64, lane, wp + WP_RW2, rb2, wv * 2, acc);
#pragma unroll
        for (int u = 0; u < 2; ++u) {
            int j = wv*2 + u;
            float v = acc[u];
            if (j < 3) v = 1.002f * (1.f / (1.f + expf(-v))) - 0.001f;
            out[OUT_RGB_OFF + (size_t)q*32 + j] = v;
        }
    }
}

// ------------------------------------------------------------------
extern "C" void kernel_launch(void* const* d_in, const int* in_sizes, int n_in,
                              void* d_out, int out_size, void* d_ws, size_t ws_size,
                              hipStream_t stream) {
    (void)in_sizes; (void)n_in; (void)out_size;
    const float* coords = (const float*)d_in[0];
    const float* dirs   = (const float*)d_in[1];
    const float* pts    = (const float*)d_in[2];
    const float* tex    = (const float*)d_in[3];
    const float* emb    = (const float*)d_in[4];
    const float* pw1 = (const float*)d_in[5];  const float* pb1 = (const float*)d_in[6];
    const float* pw2 = (const float*)d_in[7];  const float* pb2 = (const float*)d_in[8];
    const float* fw1 = (const float*)d_in[9];  const float* fb1 = (const float*)d_in[10];
    const float* fw2 = (const float*)d_in[11]; const float* fb2 = (const float*)d_in[12];
    const float* fw3 = (const float*)d_in[13]; const float* fb3 = (const float*)d_in[14];
    const float* dw  = (const float*)d_in[15]; const float* db  = (const float*)d_in[16];
    const float* rw1 = (const float*)d_in[17]; const float* rb1 = (const float*)d_in[18];
    const float* rw2 = (const float*)d_in[19]; const float* rb2 = (const float*)d_in[20];

    float*        out     = (float*)d_out;
    int*          wsidx   = (int*)d_ws;
    float*        wssums  = (float*)((char*)d_ws + WS_SUMS_OFF);
    unsigned int* wscnt   = (unsigned int*)((char*)d_ws + WS_CNT_OFF);
    unsigned int* wsstart = (unsigned int*)((char*)d_ws + WS_START_OFF);
    unsigned int* wscur   = (unsigned int*)((char*)d_ws + WS_CURSOR_OFF);
    float4*       wspg    = (float4*)((char*)d_ws + WS_PG_OFF);
    int*          wspid   = (int*)((char*)d_ws + WS_PID_OFF);
    unsigned int* wswp    = (unsigned int*)((char*)d_ws + WS_WP_OFF);
    float*        wstex   = (float*)((char*)d_ws + WS_TEX_OFF);

    const size_t need_tex = WS_TEX_OFF + (size_t)6 * HWSZ * 32 * 4;
    const int use_t = (ws_size >= need_tex) ? 1 : 0;

    PackArgs pa;
    pa.src[0] = pw1; pa.off[0] = WP_PW1; pa.din[0] = 59;  pa.dout[0] = 64;
    pa.src[1] = pw2; pa.off[1] = WP_PW2; pa.din[1] = 64;  pa.dout[1] = 32;
    pa.src[2] = fw1; pa.off[2] = WP_FW1; pa.din[2] = 64;  pa.dout[2] = 128;
    pa.src[3] = fw2; pa.off[3] = WP_FW2; pa.din[3] = 128; pa.dout[3] = 128;
    pa.src[4] = fw3; pa.off[4] = WP_FW3; pa.din[4] = 128; pa.dout[4] = 128;
    pa.src[5] = dw;  pa.off[5] = WP_DW;  pa.din[5] = 128; pa.dout[5] = 1;
    pa.src[6] = rw1; pa.off[6] = WP_RW1; pa.din[6] = 155; pa.dout[6] = 64;
    pa.src[7] = rw2; pa.off[7] = WP_RW2; pa.din[7] = 64;  pa.dout[7] = 32;

    hipMemsetAsync(wscnt, 0, 2 * GC * sizeof(unsigned int), stream);
    k_pack<<<dim3(32, 8), 256, 0, stream>>>(pa, wswp);
    if (use_t) k_transpose<<<6 * 256, 256, 0, stream>>>(tex, wstex);
    k_gcount<<<(NB*PP + 255)/256, 256, 0, stream>>>(pts, wscnt);
    k_gscan<<<1, 1024, 0, stream>>>(wscnt, wsstart, wscur);
    k_gscatter<<<(NB*PP + 255)/256, 256, 0, stream>>>(pts, wscur, wspg, wspid);
    k_knn_grid<<<NQ / 256, 256, 0, stream>>>(coords, wsstart, wscnt, wspg, wspid,
                                             out + OUT_DIST_OFF, wsidx);
    k_sums<<<8, 1024, 0, stream>>>(out + OUT_DIST_OFF, wssums);
    k_main<<<NQ / 64, 1024, 0, stream>>>(coords, dirs, pts, tex, wstex, emb,
                                         wswp, pb1, pb2, fb1, fb2, fb3, db, rb1, rb2,
                                         wsidx, out + OUT_DIST_OFF, wssums, out, use_t);
}

// Round 10
// 430.227 us; speedup vs baseline: 1.2877x; 1.2877x over previous
//
#include <hip/hip_runtime.h>
#include <float.h>
#include <math.h>

#define NB 2
#define MQ 16384
#define NQ (NB*MQ)          // 32768 queries
#define PP 5023
#define KNN 4
#define HPX 256
#define HWSZ (HPX*HPX)      // 65536
#define GD 12               // grid dim
#define GC (GD*GD*GD)       // 1728 cells
#define CAND_MAX 1024

// output layout (floats): densities[NQ], rgb[NQ*32], dist[NQ*4]
#define OUT_RGB_OFF  ((size_t)NQ)
#define OUT_DIST_OFF ((size_t)NQ + (size_t)NQ*32)

// workspace layout (bytes)
#define WS_SUMS_OFF   ((size_t)0x80000)
#define WS_PCNT_OFF   ((size_t)0x81000)
#define WS_PSTART_OFF ((size_t)0x85000)
#define WS_PCUR_OFF   ((size_t)0x89000)
#define WS_QCNT_OFF   ((size_t)0x8D000)
#define WS_QSTART_OFF ((size_t)0x91000)
#define WS_QCUR_OFF   ((size_t)0x95000)
#define WS_QID_OFF    ((size_t)0x99000)      // 32768*4 = 128 KB
#define WS_PG_OFF     ((size_t)0xC0000)      // 2*5023*16
#define WS_PID_OFF    ((size_t)0xF0000)      // 2*5023*4
#define WS_WP_OFF     ((size_t)0x100000)     // 29504 u32
#define WS_TEX_OFF    ((size_t)0x120000)     // 48 MB transposed tex

// packed-weight sub-offsets (u32 units)
#define WP_PW1 0
#define WP_PW2 1920
#define WP_FW1 2944
#define WP_FW2 7040
#define WP_FW3 15232
#define WP_DW  23424
#define WP_RW1 23488
#define WP_RW2 28480

typedef __attribute__((ext_vector_type(2))) _Float16 half2v;

static __device__ __forceinline__ unsigned int pk2(float a, float b) {
    half2v h; h[0] = (_Float16)a; h[1] = (_Float16)b;   // RNE converts
    return __builtin_bit_cast(unsigned int, h);
}
static __device__ __forceinline__ float2 upk(unsigned int u) {
    half2v h = __builtin_bit_cast(half2v, u);
    return make_float2((float)h[0], (float)h[1]);
}
static __device__ __forceinline__ float dot2(unsigned int a, unsigned int b, float c) {
    return __builtin_amdgcn_fdot2(__builtin_bit_cast(half2v, a),
                                  __builtin_bit_cast(half2v, b), c, false);
}
static __device__ __forceinline__ int cell_of(float x) {
    int g = (int)(x * (float)GD);
    return (g < 0) ? 0 : ((g > GD-1) ? GD-1 : g);
}

// ------------------------------------------------------------------
struct PackArgs {
    const float* src[8];
    int off[8]; int din[8]; int dout[8];
};
__global__ __launch_bounds__(256) void k_pack(PackArgs a, unsigned int* wp) {
    const int mid = blockIdx.y;
    const int idx = blockIdx.x * 256 + threadIdx.x;
    const int DIN = a.din[mid], DOUT = a.dout[mid];
    const int din2 = (DIN + 1) >> 1;
    if (idx >= din2 * DOUT) return;
    const int i2 = idx / DOUT, j = idx - i2 * DOUT;
    const float* s = a.src[mid];
    const float lo = s[(2*i2) * DOUT + j];
    const float hi = (2*i2 + 1 < DIN) ? s[(2*i2 + 1) * DOUT + j] : 0.f;
    wp[a.off[mid] + idx] = pk2(lo, hi);
}

// ------------------------------------------------------------------
__global__ __launch_bounds__(256) void k_transpose(const float* __restrict__ src,
                                                   float* __restrict__ dst) {
    const int tid = threadIdx.x;
    const int b = blockIdx.x;            // 6*256 blocks
    const int n3 = b >> 8;
    const int hw = ((b & 255) << 8) + tid;
    const float* s = src + (size_t)n3 * 32 * HWSZ + hw;
    float v[32];
#pragma unroll
    for (int c = 0; c < 32; ++c) v[c] = s[(size_t)c * HWSZ];
    float4* d = (float4*)(dst + ((size_t)n3 * HWSZ + hw) * 32);
#pragma unroll
    for (int c = 0; c < 8; ++c) d[c] = make_float4(v[4*c], v[4*c+1], v[4*c+2], v[4*c+3]);
}

// ------------------------------------------------------------------
// bucket builds
__global__ __launch_bounds__(256) void k_gcount(const float* __restrict__ pts,
                                                unsigned int* __restrict__ cnt) {
    const int i = blockIdx.x * 256 + threadIdx.x;
    if (i >= NB * PP) return;
    const int n = (i >= PP) ? 1 : 0;
    const float px = pts[3*i], py = pts[3*i+1], pz = pts[3*i+2];
    const int c = (cell_of(pz)*GD + cell_of(py))*GD + cell_of(px);
    atomicAdd(&cnt[n*GC + c], 1u);
}
__global__ __launch_bounds__(256) void k_qcount(const float* __restrict__ coords,
                                                unsigned int* __restrict__ cnt) {
    const int q = blockIdx.x * 256 + threadIdx.x;
    if (q >= NQ) return;
    const int n = q >> 14;
    const float cx = coords[3*q], cy = coords[3*q+1], cz = coords[3*q+2];
    const int c = (cell_of(cz)*GD + cell_of(cy))*GD + cell_of(cx);
    atomicAdd(&cnt[n*GC + c], 1u);
}

__global__ __launch_bounds__(1024) void k_scan(const unsigned int* __restrict__ cnt,
                                               unsigned int* __restrict__ start,
                                               unsigned int* __restrict__ cursor,
                                               int stride) {
    __shared__ unsigned int sc[1024];
    const int t = threadIdx.x;
#pragma unroll 1
    for (int n = 0; n < 2; ++n) {
        const unsigned int* c = cnt + n*GC;
        unsigned int a = (2*t   < GC) ? c[2*t]   : 0u;
        unsigned int b = (2*t+1 < GC) ? c[2*t+1] : 0u;
        unsigned int s = a + b;
        sc[t] = s;
        __syncthreads();
        for (int off = 1; off < 1024; off <<= 1) {
            unsigned int v = (t >= off) ? sc[t - off] : 0u;
            __syncthreads();
            sc[t] += v;
            __syncthreads();
        }
        unsigned int excl = sc[t] - s;
        unsigned int base = n * stride;
        if (2*t < GC)   { start[n*GC + 2*t]   = base + excl;
                          cursor[n*GC + 2*t]  = base + excl; }
        if (2*t+1 < GC) { start[n*GC + 2*t+1] = base + excl + a;
                          cursor[n*GC + 2*t+1]= base + excl + a; }
        __syncthreads();
    }
}

__global__ __launch_bounds__(256) void k_gscatter(const float* __restrict__ pts,
                                                  unsigned int* __restrict__ cursor,
                                                  float4* __restrict__ pg,
                                                  int* __restrict__ pid) {
    const int i = blockIdx.x * 256 + threadIdx.x;
    if (i >= NB * PP) return;
    const int n = (i >= PP) ? 1 : 0;
    const int local = i - n * PP;
    const float px = pts[3*i], py = pts[3*i+1], pz = pts[3*i+2];
    const int c = (cell_of(pz)*GD + cell_of(py))*GD + cell_of(px);
    const unsigned int pos = atomicAdd(&cursor[n*GC + c], 1u);
    pg[pos] = make_float4(px, py, pz, fmaf(px, px, fmaf(py, py, pz*pz)));
    pid[pos] = local;
}
__global__ __launch_bounds__(256) void k_qscatter(const float* __restrict__ coords,
                                                  unsigned int* __restrict__ cursor,
                                                  int* __restrict__ qid) {
    const int q = blockIdx.x * 256 + threadIdx.x;
    if (q >= NQ) return;
    const int n = q >> 14;
    const float cx = coords[3*q], cy = coords[3*q+1], cz = coords[3*q+2];
    const int c = (cell_of(cz)*GD + cell_of(cy))*GD + cell_of(cx);
    const unsigned int pos = atomicAdd(&cursor[n*GC + c], 1u);
    qid[pos] = q;
}

// ------------------------------------------------------------------
// KNN v8: one block per (n,cell). Ring<=2 candidate set staged in LDS
// (block-uniform traversal); 16-lane group per query, candidate-parallel
// exact (d2,idx) top-4 + butterfly merge. Fallback full scan if d4 too big.
__global__ __launch_bounds__(256) void k_knn_cell(
    const float* __restrict__ coords,
    const unsigned int* __restrict__ pstart, const unsigned int* __restrict__ pcnt,
    const float4* __restrict__ pg, const int* __restrict__ pid,
    const unsigned int* __restrict__ qstart, const unsigned int* __restrict__ qcnt,
    const int* __restrict__ qid,
    float* __restrict__ odist, int* __restrict__ oidx)
{
    __shared__ float4 cand[CAND_MAX];        // 16 KB
    __shared__ int    cidx[CAND_MAX];        // 4 KB
    __shared__ unsigned int cs[125], cc[125], co[126];
    const int tid = threadIdx.x;
    const int bid = blockIdx.x;              // 2*GC
    const int n = bid / GC, c = bid % GC;
    const unsigned int qn = qcnt[n*GC + c];
    if (qn == 0) return;
    const int gz = c / (GD*GD), gy = (c / GD) % GD, gx = c % GD;

    const int x0 = max(gx-2,0), x1 = min(gx+2,GD-1), nx = x1-x0+1;
    const int y0 = max(gy-2,0), y1 = min(gy+2,GD-1), ny = y1-y0+1;
    const int z0 = max(gz-2,0), z1 = min(gz+2,GD-1), nz = z1-z0+1;
    const int ncell = nx*ny*nz;

    if (tid < ncell) {
        const int xx = x0 + tid % nx;
        const int yy = y0 + (tid / nx) % ny;
        const int zz = z0 + tid / (nx*ny);
        const int cid = n*GC + (zz*GD + yy)*GD + xx;
        cs[tid] = pstart[cid];
        cc[tid] = pcnt[cid];
    }
    __syncthreads();
    if (tid == 0) {
        unsigned int acc = 0;
        co[0] = 0;
        for (int t = 0; t < ncell; ++t) { acc += cc[t]; co[t+1] = acc; }
    }
    __syncthreads();
    const unsigned int total = co[ncell];
    const bool ovf = (total > CAND_MAX);
    if (!ovf) {
#pragma unroll 1
        for (int t = 0; t < ncell; ++t) {
            const unsigned int m = cc[t];
            if (tid < (int)m) {
                cand[co[t] + tid] = pg[cs[t] + tid];
                cidx[co[t] + tid] = pid[cs[t] + tid];
            }
        }
    }
    __syncthreads();

    const float w = 1.0f / (float)GD;
    const float thresh = 4.f * w * w * 0.999f;
    const int grp = tid >> 4, l16 = tid & 15;
    const unsigned int qs = qstart[n*GC + c];

#define INS4(d, i) { \
        bool L3 = ((d) < bd3) || ((d) == bd3 && (i) < bi3); \
        bool L2 = ((d) < bd2) || ((d) == bd2 && (i) < bi2); \
        bool L1 = ((d) < bd1) || ((d) == bd1 && (i) < bi1); \
        bool L0 = ((d) < bd0) || ((d) == bd0 && (i) < bi0); \
        bd3 = L3 ? (L2 ? bd2 : (d)) : bd3;  bi3 = L3 ? (L2 ? bi2 : (i)) : bi3; \
        bd2 = L2 ? (L1 ? bd1 : (d)) : bd2;  bi2 = L2 ? (L1 ? bi1 : (i)) : bi2; \
        bd1 = L1 ? (L0 ? bd0 : (d)) : bd1;  bi1 = L1 ? (L0 ? bi0 : (i)) : bi1; \
        bd0 = L0 ? (d) : bd0;               bi0 = L0 ? (i) : bi0; }

#define MERGE16() { \
        float bd[4] = { bd0, bd1, bd2, bd3 }; \
        int   bi[4] = { bi0, bi1, bi2, bi3 }; \
        for (int mask = 1; mask < 16; mask <<= 1) { \
            float od[4]; int oi[4]; \
            for (int j = 0; j < 4; ++j) { od[j] = __shfl_xor(bd[j], mask); \
                                          oi[j] = __shfl_xor(bi[j], mask); } \
            float e[4]; int ei[4]; \
            for (int j = 0; j < 4; ++j) { \
                float ad = bd[j], xd = od[3-j]; \
                int   ai = bi[j], xi = oi[3-j]; \
                bool ta = (ad < xd) || (ad == xd && ai < xi); \
                e[j] = ta ? ad : xd; ei[j] = ta ? ai : xi; \
            } \
            { bool sw = (e[2] < e[0]) || (e[2] == e[0] && ei[2] < ei[0]); \
              if (sw) { float td=e[0]; e[0]=e[2]; e[2]=td; int ti=ei[0]; ei[0]=ei[2]; ei[2]=ti; } } \
            { bool sw = (e[3] < e[1]) || (e[3] == e[1] && ei[3] < ei[1]); \
              if (sw) { float td=e[1]; e[1]=e[3]; e[3]=td; int ti=ei[1]; ei[1]=ei[3]; ei[3]=ti; } } \
            { bool sw = (e[1] < e[0]) || (e[1] == e[0] && ei[1] < ei[0]); \
              if (sw) { float td=e[0]; e[0]=e[1]; e[1]=td; int ti=ei[0]; ei[0]=ei[1]; ei[1]=ti; } } \
            { bool sw = (e[3] < e[2]) || (e[3] == e[2] && ei[3] < ei[2]); \
              if (sw) { float td=e[2]; e[2]=e[3]; e[3]=td; int ti=ei[2]; ei[2]=ei[3]; ei[3]=ti; } } \
            for (int j = 0; j < 4; ++j) { bd[j] = e[j]; bi[j] = ei[j]; } \
        } \
        bd0 = bd[0]; bd1 = bd[1]; bd2 = bd[2]; bd3 = bd[3]; \
        bi0 = bi[0]; bi1 = bi[1]; bi2 = bi[2]; bi3 = bi[3]; }

#pragma unroll 1
    for (unsigned int qb = 0; qb < qn; qb += 16) {
        const unsigned int qi = qb + grp;
        if (qi >= qn) continue;
        const int q = qid[qs + qi];
        const float cx = coords[3*q], cy = coords[3*q+1], cz = coords[3*q+2];
        const float ccq = fmaf(cx, cx, fmaf(cy, cy, cz*cz));

        float bd0 = FLT_MAX, bd1 = FLT_MAX, bd2 = FLT_MAX, bd3 = FLT_MAX;
        int   bi0 = 0x7fffffff, bi1 = 0x7fffffff, bi2 = 0x7fffffff, bi3 = 0x7fffffff;

        if (!ovf) {
#pragma unroll 1
            for (unsigned int j = l16; j < total; j += 16) {
                const float4 P = cand[j];
                const int i = cidx[j];
                const float dt = fmaf(cx, P.x, fmaf(cy, P.y, cz * P.z));
                const float d = fmaf(-2.0f, dt, ccq + P.w);
                INS4(d, i)
            }
            MERGE16()
        }
        if (ovf || !(bd3 < thresh)) {
            // fallback: exact full scan over all PP points of this batch
            bd0 = bd1 = bd2 = bd3 = FLT_MAX;
            bi0 = bi1 = bi2 = bi3 = 0x7fffffff;
#pragma unroll 1
            for (int j = l16; j < PP; j += 16) {
                const float4 P = pg[n*PP + j];
                const int i = pid[n*PP + j];
                const float dt = fmaf(cx, P.x, fmaf(cy, P.y, cz * P.z));
                const float d = fmaf(-2.0f, dt, ccq + P.w);
                INS4(d, i)
            }
            MERGE16()
        }
        if (l16 == 0) {
            *(float4*)(odist + (size_t)q*4) = make_float4(bd0, bd1, bd2, bd3);
            *(int4*)(oidx + (size_t)q*4)    = make_int4(bi0, bi1, bi2, bi3);
        }
    }
#undef INS4
#undef MERGE16
}

// ------------------------------------------------------------------
__global__ __launch_bounds__(1024) void k_sums(const float* __restrict__ dist,
                                               float* __restrict__ sums) {
    const int b = blockIdx.x;            // n*4+k, 8 blocks
    const int n = b >> 2, k = b & 3;
    float s = 0.f;
    for (int m = threadIdx.x; m < MQ; m += 1024)
        s += 1.0f / dist[((size_t)n * MQ + m) * 4 + k];
    __shared__ float red[1024];
    red[threadIdx.x] = s;
    __syncthreads();
    for (int off = 512; off > 0; off >>= 1) {
        if (threadIdx.x < off) red[threadIdx.x] += red[threadIdx.x + off];
        __syncthreads();
    }
    if (threadIdx.x == 0) sums[b] = red[0];
}

// ------------------------------------------------------------------
// packed gemv: activations f16x2 from LDS; weights via per-lane uint4
// vector loads (global_load_dwordx4, L1-broadcast, vmcnt-pipelined).
template<int DIN2, int DOUT, int TILE>
__device__ __forceinline__ void gemv_p4(const unsigned int* __restrict__ Xp, int lane,
                                        const unsigned int* __restrict__ Wp,
                                        const float* __restrict__ bias,
                                        int j0, float (&acc)[TILE]) {
    static_assert(TILE % 4 == 0, "");
#pragma unroll
    for (int u = 0; u < TILE; ++u) acc[u] = bias[j0 + u];
#pragma unroll
    for (int i2 = 0; i2 < DIN2; ++i2) {
        const unsigned int xv = Xp[i2 * 64 + lane];
        const uint4* wr = (const uint4*)(Wp + i2 * DOUT + j0);
#pragma unroll
        for (int t = 0; t < TILE/4; ++t) {
            const uint4 wv4 = wr[t];
            acc[4*t+0] = dot2(xv, wv4.x, acc[4*t+0]);
            acc[4*t+1] = dot2(xv, wv4.y, acc[4*t+1]);
            acc[4*t+2] = dot2(xv, wv4.z, acc[4*t+2]);
            acc[4*t+3] = dot2(xv, wv4.w, acc[4*t+3]);
        }
    }
}
template<int DIN2, int DOUT, int TILE>
__device__ __forceinline__ void gemv_p(const unsigned int* __restrict__ Xp, int lane,
                                       const unsigned int* __restrict__ Wp,
                                       const float* __restrict__ bias,
                                       int j0, float (&acc)[TILE]) {
#pragma unroll
    for (int u = 0; u < TILE; ++u) acc[u] = bias[j0 + u];
#pragma unroll
    for (int i2 = 0; i2 < DIN2; ++i2) {
        const unsigned int xv = Xp[i2 * 64 + lane];
        const unsigned int* wr = Wp + i2 * DOUT + j0;
#pragma unroll
        for (int u = 0; u < TILE; ++u) acc[u] = dot2(xv, wr[u], acc[u]);
    }
}

static __device__ __forceinline__ float harm_val(int h, float rx, float ry, float rz) {
    if (h >= 27) return 0.f;
    float v;
    if (h < 24) {
        int base = (h < 12) ? h : (h - 12);
        float rv = (base >> 2) == 0 ? rx : ((base >> 2) == 1 ? ry : rz);
        float e = rv * (float)(1 << (base & 3));
        v = (h < 12) ? sinf(e) : cosf(e);
    } else {
        v = (h == 24) ? rx : ((h == 25) ? ry : rz);
    }
    return v;
}

// ------------------------------------------------------------------
// main fused kernel v10: divergent wv (vector weight loads), uint4 weights.
__global__ __launch_bounds__(1024, 1) void k_main(
    const float* __restrict__ coords, const float* __restrict__ dirs,
    const float* __restrict__ pts, const float* __restrict__ tex_raw,
    const float* __restrict__ tex_t, const float* __restrict__ emb,
    const unsigned int* __restrict__ wp,
    const float* __restrict__ pb1, const float* __restrict__ pb2,
    const float* __restrict__ fb1, const float* __restrict__ fb2,
    const float* __restrict__ fb3, const float* __restrict__ db,
    const float* __restrict__ rb1, const float* __restrict__ rb2,
    const int* __restrict__ idxbuf, const float* __restrict__ distbuf,
    const float* __restrict__ sums, float* __restrict__ out, int use_tex_t)
{
    __shared__ unsigned int S[248 * 64];   // 62 KB
    const int tid  = threadIdx.x;
    const int lane = tid & 63;
    const int wv   = tid >> 6;             // divergent on purpose (vector loads)
    const int q0   = blockIdx.x * 64;
    const int n    = q0 >> 14;
    const int q    = q0 + lane;

    // ---------- phase 0: triplane sampling ----------
    float tex_acc[2] = {0.f, 0.f};
    {
        const int g = wv;
        const float cx = coords[q*3+0], cy = coords[q*3+1], cz = coords[q*3+2];
#pragma unroll
        for (int pl = 0; pl < 3; ++pl) {
            float gx = (pl == 2) ? cz : cx;
            float gy = (pl == 0) ? cy : ((pl == 1) ? cz : cx);
            float x = (gx + 1.f) * 128.f - 0.5f;
            float y = (gy + 1.f) * 128.f - 0.5f;
            float x0f = floorf(x), y0f = floorf(y);
            float wx1 = x - x0f, wy1 = y - y0f;
            float wx0 = 1.f - wx1, wy0 = 1.f - wy1;
            int x0 = (int)x0f, y0 = (int)y0f;
            int n3 = n * 3 + pl;
            int  xs[4] = { x0, x0+1, x0,   x0+1 };
            int  ys[4] = { y0, y0,   y0+1, y0+1 };
            float wt[4] = { wx0*wy0, wx1*wy0, wx0*wy1, wx1*wy1 };
#pragma unroll
            for (int c = 0; c < 4; ++c) {
                int xi = xs[c], yi = ys[c];
                if (xi >= 0 && xi < HPX && yi >= 0 && yi < HPX) {
                    float wgt = wt[c];
                    if (use_tex_t) {
                        const float2 a = *(const float2*)(tex_t +
                            (((size_t)n3 * HWSZ + (size_t)yi * HPX + xi) * 32 + g * 2));
                        tex_acc[0] = fmaf(wgt, a.x, tex_acc[0]);
                        tex_acc[1] = fmaf(wgt, a.y, tex_acc[1]);
                    } else {
                        size_t base = ((size_t)(n3 * 32 + g * 2)) * HWSZ + (size_t)yi * HPX + xi;
                        tex_acc[0] = fmaf(wgt, tex_raw[base], tex_acc[0]);
                        tex_acc[1] = fmaf(wgt, tex_raw[base + HWSZ], tex_acc[1]);
                    }
                }
            }
        }
        tex_acc[0] *= (1.f / 3.f); tex_acc[1] *= (1.f / 3.f);
    }

    const int kk  = wv & 3;
    const int prt = wv >> 2;

    // ---------- phase A: build x59 for all 4 neighbors ----------
    {
        const int id = idxbuf[(size_t)q*4 + kk];
        const int rb = kk * 30;
        if (prt < 2) {
#pragma unroll
            for (int t = 0; t < 2; ++t) {
                const float4 e = *(const float4*)(emb + (size_t)id * 32 + prt*16 + t*4 + 0)
                    , e2 = *(const float4*)(emb + (size_t)id * 32 + prt*16 + t*4 + 8);
                S[(rb + prt*8 + t*2    )*64 + lane] = pk2(e.x,  e.y);
                S[(rb + prt*8 + t*2 + 1)*64 + lane] = pk2(e.z,  e.w);
                S[(rb + prt*8 + t*2 + 4)*64 + lane] = pk2(e2.x, e2.y);
                S[(rb + prt*8 + t*2 + 5)*64 + lane] = pk2(e2.z, e2.w);
            }
        } else {
            const float cx = coords[q*3+0], cy = coords[q*3+1], cz = coords[q*3+2];
            const float nx = pts[((size_t)n*PP + id)*3 + 0];
            const float ny = pts[((size_t)n*PP + id)*3 + 1];
            const float nz = pts[((size_t)n*PP + id)*3 + 2];
            float rx = cx - nx, ry = cy - ny, rz = cz - nz;
            float nrm = sqrtf(fmaf(rx, rx, fmaf(ry, ry, rz*rz)));
            float inv = 1.f / fmaxf(nrm, 1e-12f);
            rx *= inv; ry *= inv; rz *= inv;
            const int pr0 = (prt == 2) ? 0 : 8;
            const int prn = (prt == 2) ? 8 : 6;
#pragma unroll
            for (int t = 0; t < 8; ++t) {
                if (t < prn) {
                    int pr = pr0 + t;
                    S[(rb + 16 + pr)*64 + lane] =
                        pk2(harm_val(2*pr, rx, ry, rz), harm_val(2*pr + 1, rx, ry, rz));
                }
            }
        }
    }
    __syncthreads();

    // ---------- phase B: p1 59->64 relu ----------
    {
        float acc[16];
        gemv_p4<30, 64, 16>(S + (kk*30)*64, lane, wp + WP_PW1, pb1, prt * 16, acc);
        const int rb = 120 + kk*32 + prt*8;
#pragma unroll
        for (int u = 0; u < 8; ++u)
            S[(rb + u)*64 + lane] = pk2(fmaxf(acc[2*u], 0.f), fmaxf(acc[2*u+1], 0.f));
    }
    __syncthreads();

    // ---------- phase C: p2 64->32 wk-scaled ----------
    {
        float acc[8];
        gemv_p4<32, 32, 8>(S + (120 + kk*32)*64, lane, wp + WP_PW2, pb2, prt * 8, acc);
        const float dist = distbuf[(size_t)q*4 + kk];
        const float wk = (1.0f / dist) / sums[n*4 + kk];
        const int rb = kk*16 + prt*4;
#pragma unroll
        for (int u = 0; u < 4; ++u)
            S[(rb + u)*64 + lane] = pk2(wk * acc[2*u], wk * acc[2*u+1]);
    }
    __syncthreads();

    // ---------- phase D: feat ----------
    {
        S[(128 + wv)*64 + lane] = pk2(tex_acc[0], tex_acc[1]);
        float a = 0.f, b = 0.f;
#pragma unroll
        for (int k = 0; k < 4; ++k) {
            float2 v = upk(S[(k*16 + wv)*64 + lane]);
            a += v.x; b += v.y;
        }
        S[(144 + wv)*64 + lane] = pk2(a, b);
    }
    __syncthreads();

    // ---------- phase E: fw1 64->128 relu ----------
    {
        float acc[8];
        gemv_p4<32, 128, 8>(S + 128*64, lane, wp + WP_FW1, fb1, wv * 8, acc);
#pragma unroll
        for (int u = 0; u < 4; ++u)
            S[(4*wv + u)*64 + lane] = pk2(fmaxf(acc[2*u], 0.f), fmaxf(acc[2*u+1], 0.f));
    }
    __syncthreads();
    // ---------- phase F: fw2 ----------
    {
        float acc[8];
        gemv_p4<64, 128, 8>(S, lane, wp + WP_FW2, fb2, wv * 8, acc);
#pragma unroll
        for (int u = 0; u < 4; ++u)
            S[(64 + 4*wv + u)*64 + lane] = pk2(fmaxf(acc[2*u], 0.f), fmaxf(acc[2*u+1], 0.f));
    }
    __syncthreads();
    // ---------- phase G: fw3 ----------
    {
        float acc[8];
        gemv_p4<64, 128, 8>(S + 64*64, lane, wp + WP_FW3, fb3, wv * 8, acc);
#pragma unroll
        for (int u = 0; u < 4; ++u)
            S[(4*wv + u)*64 + lane] = pk2(acc[2*u], acc[2*u+1]);
    }
    __syncthreads();
    // ---------- phase H: ray harm + density ----------
    {
        if (wv < 14) {
            float dx = dirs[q*3+0], dy = dirs[q*3+1], dz = dirs[q*3+2];
            float dn = sqrtf(fmaf(dx, dx, fmaf(dy, dy, dz*dz)));
            float inv = 1.f / fmaxf(dn, 1e-12f);
            dx *= inv; dy *= inv; dz *= inv;
            S[(128 + wv)*64 + lane] = pk2(harm_val(2*wv, dx, dy, dz),
                                          harm_val(2*wv + 1, dx, dy, dz));
        } else if (wv == 15) {
            float z = db[0];
            const unsigned int* dwp = wp + WP_DW;
#pragma unroll 1
            for (int i2 = 0; i2 < 64; ++i2) z = dot2(S[i2*64 + lane], dwp[i2], z);
            const float cx = coords[q*3+0], cy = coords[q*3+1], cz = coords[q*3+2];
            float selv = (cx > -1.f && cx < 1.f && cy > -1.f && cy < 1.f &&
                          cz > -1.f && cz < 1.f) ? 1.f : 0.f;
            float t10 = 10.f * z;
            float sp = (t10 > 20.f) ? t10 : log1pf(expf(t10));
            float raw = sp * 0.1f * selv;
            out[q] = 1.f - expf(-raw);
        }
    }
    __syncthreads();
    // ---------- phase I: rw1 155->64 relu ----------
    {
        const int j0 = wv * 4;
        float acc[4];
        gemv_p4<64, 64, 4>(S, lane, wp + WP_RW1, rb1, j0, acc);
#pragma unroll
        for (int t = 0; t < 14; ++t) {
            const unsigned int xv = S[(128 + t)*64 + lane];
            const uint4 wv4 = *(const uint4*)(wp + WP_RW1 + (64 + t) * 64 + j0);
            acc[0] = dot2(xv, wv4.x, acc[0]);
            acc[1] = dot2(xv, wv4.y, acc[1]);
            acc[2] = dot2(xv, wv4.z, acc[2]);
            acc[3] = dot2(xv, wv4.w, acc[3]);
        }
        S[(64 + 2*wv    )*64 + lane] = pk2(fmaxf(acc[0], 0.f), fmaxf(acc[1], 0.f));
        S[(64 + 2*wv + 1)*64 + lane] = pk2(fmaxf(acc[2], 0.f), fmaxf(acc[3], 0.f));
    }
    __syncthreads();
    // ---------- phase J: rw2 64->32 ----------
    {
        float acc[2];
        gemv_p<32, 32, 2>(S + 64*64, lane, wp + WP_RW2, rb2, wv * 2, acc);
#pragma unroll
        for (int u = 0; u < 2; ++u) {
            int j = wv*2 + u;
            float v = acc[u];
            if (j < 3) v = 1.002f * (1.f / (1.f + expf(-v))) - 0.001f;
            out[OUT_RGB_OFF + (size_t)q*32 + j] = v;
        }
    }
}

// ------------------------------------------------------------------
extern "C" void kernel_launch(void* const* d_in, const int* in_sizes, int n_in,
                              void* d_out, int out_size, void* d_ws, size_t ws_size,
                              hipStream_t stream) {
    (void)in_sizes; (void)n_in; (void)out_size;
    const float* coords = (const float*)d_in[0];
    const float* dirs   = (const float*)d_in[1];
    const float* pts    = (const float*)d_in[2];
    const float* tex    = (const float*)d_in[3];
    const float* emb    = (const float*)d_in[4];
    const float* pw1 = (const float*)d_in[5];  const float* pb1 = (const float*)d_in[6];
    const float* pw2 = (const float*)d_in[7];  const float* pb2 = (const float*)d_in[8];
    const float* fw1 = (const float*)d_in[9];  const float* fb1 = (const float*)d_in[10];
    const float* fw2 = (const float*)d_in[11]; const float* fb2 = (const float*)d_in[12];
    const float* fw3 = (const float*)d_in[13]; const float* fb3 = (const float*)d_in[14];
    const float* dw  = (const float*)d_in[15]; const float* db  = (const float*)d_in[16];
    const float* rw1 = (const float*)d_in[17]; const float* rb1 = (const float*)d_in[18];
    const float* rw2 = (const float*)d_in[19]; const float* rb2 = (const float*)d_in[20];

    float*        out     = (float*)d_out;
    int*          wsidx   = (int*)d_ws;
    float*        wssums  = (float*)((char*)d_ws + WS_SUMS_OFF);
    unsigned int* wspcnt  = (unsigned int*)((char*)d_ws + WS_PCNT_OFF);
    unsigned int* wspsta  = (unsigned int*)((char*)d_ws + WS_PSTART_OFF);
    unsigned int* wspcur  = (unsigned int*)((char*)d_ws + WS_PCUR_OFF);
    unsigned int* wsqcnt  = (unsigned int*)((char*)d_ws + WS_QCNT_OFF);
    unsigned int* wsqsta  = (unsigned int*)((char*)d_ws + WS_QSTART_OFF);
    unsigned int* wsqcur  = (unsigned int*)((char*)d_ws + WS_QCUR_OFF);
    int*          wsqid   = (int*)((char*)d_ws + WS_QID_OFF);
    float4*       wspg    = (float4*)((char*)d_ws + WS_PG_OFF);
    int*          wspid   = (int*)((char*)d_ws + WS_PID_OFF);
    unsigned int* wswp    = (unsigned int*)((char*)d_ws + WS_WP_OFF);
    float*        wstex   = (float*)((char*)d_ws + WS_TEX_OFF);

    const size_t need_tex = WS_TEX_OFF + (size_t)6 * HWSZ * 32 * 4;
    const int use_t = (ws_size >= need_tex) ? 1 : 0;

    PackArgs pa;
    pa.src[0] = pw1; pa.off[0] = WP_PW1; pa.din[0] = 59;  pa.dout[0] = 64;
    pa.src[1] = pw2; pa.off[1] = WP_PW2; pa.din[1] = 64;  pa.dout[1] = 32;
    pa.src[2] = fw1; pa.off[2] = WP_FW1; pa.din[2] = 64;  pa.dout[2] = 128;
    pa.src[3] = fw2; pa.off[3] = WP_FW2; pa.din[3] = 128; pa.dout[3] = 128;
    pa.src[4] = fw3; pa.off[4] = WP_FW3; pa.din[4] = 128; pa.dout[4] = 128;
    pa.src[5] = dw;  pa.off[5] = WP_DW;  pa.din[5] = 128; pa.dout[5] = 1;
    pa.src[6] = rw1; pa.off[6] = WP_RW1; pa.din[6] = 155; pa.dout[6] = 64;
    pa.src[7] = rw2; pa.off[7] = WP_RW2; pa.din[7] = 64;  pa.dout[7] = 32;

    // zero both count arrays (region covers pcnt..qcnt)
    hipMemsetAsync((char*)d_ws + WS_PCNT_OFF, 0, WS_QSTART_OFF - WS_PCNT_OFF, stream);
    k_pack<<<dim3(32, 8), 256, 0, stream>>>(pa, wswp);
    if (use_t) k_transpose<<<6 * 256, 256, 0, stream>>>(tex, wstex);
    k_gcount<<<(NB*PP + 255)/256, 256, 0, stream>>>(pts, wspcnt);
    k_qcount<<<NQ/256, 256, 0, stream>>>(coords, wsqcnt);
    k_scan<<<1, 1024, 0, stream>>>(wspcnt, wspsta, wspcur, PP);
    k_scan<<<1, 1024, 0, stream>>>(wsqcnt, wsqsta, wsqcur, MQ);
    k_gscatter<<<(NB*PP + 255)/256, 256, 0, stream>>>(pts, wspcur, wspg, wspid);
    k_qscatter<<<NQ/256, 256, 0, stream>>>(coords, wsqcur, wsqid);
    k_knn_cell<<<NB*GC, 256, 0, stream>>>(coords, wspsta, wspcnt, wspg, wspid,
                                          wsqsta, wsqcnt, wsqid,
                                          out + OUT_DIST_OFF, wsidx);
    k_sums<<<8, 1024, 0, stream>>>(out + OUT_DIST_OFF, wssums);
    k_main<<<NQ / 64, 1024, 0, stream>>>(coords, dirs, pts, tex, wstex, emb,
                                         wswp, pb1, pb2, fb1, fb2, fb3, db, rb1, rb2,
                                         wsidx, out + OUT_DIST_OFF, wssums, out, use_t);
}